// Round 6
// baseline (154.865 us; speedup 1.0000x reference)
//
#include <hip/hip_runtime.h>
#include <stdint.h>

#define V3 110592        // 48*48*48
#define PLANE 2304       // 48*48
#define NO 64

typedef unsigned short ushort_t;
typedef __attribute__((ext_vector_type(8))) short short8v;
typedef __attribute__((ext_vector_type(4))) float float4v;

__device__ __forceinline__ uint32_t f2bf1(float f) {
  uint32_t u = __float_as_uint(f);
  u += 0x7FFFu + ((u >> 16) & 1u);   // RNE
  return u >> 16;
}
__device__ __forceinline__ uint32_t pack2(float a, float b) {
  return f2bf1(a) | (f2bf1(b) << 16);
}

// prep folded into bq (R6): blocks (x, y<5, z==0) cover idx = (y*48+x)*256+tid
// = exactly [0, 61440) -> one fewer dispatch boundary.
__device__ __forceinline__ void prep_body(const float* __restrict__ w,
                                          ushort_t* __restrict__ Afr, int idx) {
  int r = idx & 7, m = (idx >> 3) & 63, g = idx >> 9;
  int kk = g * 8 + r;
  int dzi = kk / 192, k2 = kk % 192;
  int i = k2 / 6, qi = k2 % 6;
  const int Q[6] = {0, 1, 2, 4, 5, 8};
  const int pidx[13] = {0, 1, 2, 3, 4, 5, 6, 0, 7, 8, 0, 0, 9};  // r2 -> shell
  int dz = dzi - 2;
  int p = pidx[Q[qi] + dz * dz];
  Afr[idx] = (ushort_t)f2bf1(0.28209479177387814f * w[(m * 32 + i) * 10 + p]);
}

// ---------- pass 1: per-plane 2D class sums; NO LDS, NO barriers ----------
// R4 (verified): two-phase (all 40 loads first, then shfl/reduce/store) took
// bq to ~its memory floor (~16-18 us per batch). Kept as-is.
__global__ __launch_bounds__(256, 4) void bq_kernel(const float* __restrict__ x,
                                                    ushort_t* __restrict__ Bq,
                                                    const float* __restrict__ w,
                                                    ushort_t* __restrict__ Afr) {
  const int tid = threadIdx.x;
  if (blockIdx.z == 0 && blockIdx.y < 5)
    prep_body(w, Afr, (blockIdx.y * 48 + blockIdx.x) * 256 + tid);

  const int lane = tid & 63;
  const int strip = tid >> 6;                    // 0..3 within block
  const int d = blockIdx.x;                      // 0..47
  const int ig = blockIdx.y & 7;                 // 0..7 channel group
  const int half = blockIdx.y >> 3;              // 0..1 strip half
  const float* xb = x + (size_t)blockIdx.z * 32 * V3;
  ushort_t* Bqb = Bq + (size_t)blockIdx.z * ((size_t)1152 * PLANE * 8);

  const int h0 = (half * 4 + strip) * 6;         // 6-row strip base
  const int gw = lane - 2;
  const bool okw = (gw >= 0 && gw < 48);
  const int sl1 = lane > 0 ? lane - 1 : 0;
  const int sl2 = lane > 1 ? lane - 2 : 0;
  const int sr1 = lane < 63 ? lane + 1 : 63;
  const int sr2 = lane < 62 ? lane + 2 : 63;
  const bool okst = (lane >= 2 && lane <= 49);

  const float* px[4];
#pragma unroll
  for (int ii = 0; ii < 4; ++ii)
    px[ii] = xb + ((size_t)(ig * 4 + ii) * 48 + d) * PLANE + gw;

  // phase 1: all loads in flight (independent addresses, one vmcnt chain)
  float v[10][4];
#pragma unroll
  for (int r = 0; r < 10; ++r) {
    const int gh = h0 - 2 + r;
    const bool okv = okw && (gh >= 0) && (gh < 48);
#pragma unroll
    for (int ii = 0; ii < 4; ++ii)
      v[r][ii] = okv ? px[ii][gh * 48] : 0.f;
  }

  // phase 2: shfl class-sums with rolling windows; a0 terms read v[] directly
  float s1[4][5], s4[4][5];
#pragma unroll
  for (int r = 0; r < 10; ++r) {
    const int slot = r % 5;
#pragma unroll
    for (int ii = 0; ii < 4; ++ii) {
      float val = v[r][ii];
      float vl1 = __shfl(val, sl1);
      float vr1 = __shfl(val, sr1);
      float vl2 = __shfl(val, sl2);
      float vr2 = __shfl(val, sr2);
      s1[ii][slot] = vl1 + vr1;                  // dx^2 = 1
      s4[ii][slot] = vl2 + vr2;                  // dx^2 = 4
    }
    if (r >= 4) {
      const int j0 = (r - 4) % 5, j1 = (r - 3) % 5, j2 = (r - 2) % 5,
                j3 = (r - 1) % 5, j4 = r % 5;    // j = dy offset 0..4
      uint32_t dw[12];
#pragma unroll
      for (int ii = 0; ii < 4; ++ii) {
        float B0 = v[r - 2][ii];
        float B1 = s1[ii][j2] + v[r - 3][ii] + v[r - 1][ii];
        float B2 = s1[ii][j1] + s1[ii][j3];
        float B3 = s4[ii][j2] + v[r - 4][ii] + v[r][ii];
        float B4 = s4[ii][j1] + s4[ii][j3] + s1[ii][j0] + s1[ii][j4];
        float B5 = s4[ii][j0] + s4[ii][j4];
        dw[ii * 3 + 0] = pack2(B0, B1);
        dw[ii * 3 + 1] = pack2(B2, B3);
        dw[ii * 3 + 2] = pack2(B4, B5);
      }
      if (okst) {
        const int n = (h0 + r - 4) * 48 + gw;
        const size_t gb = (size_t)(d * 24 + ig * 3);
        uint4 c0 = {dw[0], dw[1], dw[2], dw[3]};
        uint4 c1 = {dw[4], dw[5], dw[6], dw[7]};
        uint4 c2 = {dw[8], dw[9], dw[10], dw[11]};
        *(uint4*)(Bqb + ((gb + 0) * PLANE + n) * 8) = c0;
        *(uint4*)(Bqb + ((gb + 1) * PLANE + n) * 8) = c1;
        *(uint4*)(Bqb + ((gb + 2) * PLANE + n) * 8) = c2;
      }
    }
  }
}

// ---------- pass 2: plane-major GEMM, K = 960 linear walk ----------
// out[m][d,n] = sum_kk Afr[kk][m] * Bq[(d-2)*24 + kk/8][n][kk%8] + bias[m]
// XCD partition (verified R1: FETCH 207.8 -> 83.4 MB): b&7 -> XCD.
// R6: 64x64 per-WAVE register tile (was 64x32). Arithmetic: old tile moved
// 6 KB through L1 per 8 MFMA (~39 cy) = 633 B/cy/CU demand at full duty vs
// ~128 B/cy L1 -> 20% MfmaUtil cap = measured 18.7%. L1 *bandwidth*, not
// scheduling, was the wall (why R3-R5 pipeline attempts were flat). 64x64
// halves bytes/MFMA (8 KB / 16 MFMA) -> cap ~28%, and doubles per-trip MFMA
// coverage (~78 cy) for latency hiding. 2-wave blocks (128 thr), nbl spans
// 128 cols, same 864-block grid + XCD map. Depth-2 pinned ping-pong kept.
__global__ __launch_bounds__(128, 3) void gemm_kernel(const ushort_t* __restrict__ Bq,
                                                      const ushort_t* __restrict__ Afr,
                                                      const float* __restrict__ bias,
                                                      float* __restrict__ out) {
  const int tid = threadIdx.x;
  const int lane = tid & 63, wi = tid >> 6;      // wi 0..1
  const int quad = lane >> 4, m15 = lane & 15;
  const int b = blockIdx.x;                      // 0..863 flat
  const int p = b & 7;                           // XCD partition
  const int s = b >> 3;                          // 0..107 within partition
  const int dl = s / 9;                          // 0..11
  const int nbl = s - dl * 9;                    // 0..8
  const int d = (p >> 1) * 12 + dl;              // output plane
  const int n0 = ((p & 1) * 9 + nbl) * 128 + wi * 64;
  const ushort_t* Bqb = Bq + (size_t)blockIdx.z * ((size_t)1152 * PLANE * 8);
  float* outb = out + (size_t)blockIdx.z * (size_t)NO * V3;

  const int lo = (d < 2) ? (2 - d) : 0;          // dzi range [lo,hi]
  const int hi = (d > 45) ? (49 - d) : 4;
  const int kslo = 6 * lo;
  const int T = 6 * (hi - lo + 1);               // trips: 18/24/30 (even)

  const ushort_t* ap = Afr + ((size_t)(kslo * 4 + quad) * 64 + m15) * 8;
  const ushort_t* bp = Bqb + ((size_t)((d - 2) * 24 + kslo * 4 + quad) * PLANE + n0 + m15) * 8;
  const int astep = 4 * 64 * 8;                  // shorts per ks
  const int bstep = 4 * PLANE * 8;

  float4v acc[4][4];
#pragma unroll
  for (int mt = 0; mt < 4; ++mt)
#pragma unroll
    for (int nt = 0; nt < 4; ++nt) acc[mt][nt] = (float4v){0.f, 0.f, 0.f, 0.f};

  short8v A0[4], B0[4], A1[4], B1[4];

#define SBAR __builtin_amdgcn_sched_barrier(0)
#define LOADSET(Ax, Bx)                                                        \
  {                                                                            \
    _Pragma("unroll") for (int nt = 0; nt < 4; ++nt)                           \
        Bx[nt] = *(const short8v*)(bp + nt * 128);                             \
    _Pragma("unroll") for (int mt = 0; mt < 4; ++mt)                           \
        Ax[mt] = *(const short8v*)(ap + mt * 128);                             \
    ap += astep; bp += bstep;                                                  \
  }
#define MFMASET(Ax, Bx)                                                        \
  {                                                                            \
    __builtin_amdgcn_s_setprio(1);                                             \
    _Pragma("unroll") for (int mt = 0; mt < 4; ++mt)                           \
        _Pragma("unroll") for (int nt = 0; nt < 4; ++nt)                       \
            acc[mt][nt] = __builtin_amdgcn_mfma_f32_16x16x32_bf16(             \
                Ax[mt], Bx[nt], acc[mt][nt], 0, 0, 0);                         \
    __builtin_amdgcn_s_setprio(0);                                             \
  }

  // depth-2 ping-pong, order pinned
  LOADSET(A0, B0);
  SBAR;
  for (int k = 0; k + 2 < T; k += 2) {
    LOADSET(A1, B1); SBAR;
    MFMASET(A0, B0); SBAR;
    LOADSET(A0, B0); SBAR;
    MFMASET(A1, B1); SBAR;
  }
  LOADSET(A1, B1); SBAR;
  MFMASET(A0, B0);
  MFMASET(A1, B1);
#undef LOADSET
#undef MFMASET
#undef SBAR

  // C/D: col(n) = lane&15, row(m) = quad*4 + reg
  const int vb = d * PLANE + n0 + m15;
#pragma unroll
  for (int mt = 0; mt < 4; ++mt) {
#pragma unroll
    for (int r = 0; r < 4; ++r) {
      int m = mt * 16 + quad * 4 + r;
      float bv = bias[m];
      float* op = outb + (size_t)m * V3 + vb;
#pragma unroll
      for (int nt = 0; nt < 4; ++nt)
        op[nt * 16] = acc[mt][nt][r] + bv;
    }
  }
}

extern "C" void kernel_launch(void* const* d_in, const int* in_sizes, int n_in,
                              void* d_out, int out_size, void* d_ws, size_t ws_size,
                              hipStream_t stream) {
  const float* x    = (const float*)d_in[0];   // [2,32,1,48,48,48]
  const float* w    = (const float*)d_in[1];   // [64,32,1,1,1,10]
  const float* bias = (const float*)d_in[2];   // [64]
  float* out = (float*)d_out;                  // [2,64,1,48,48,48]

  ushort_t* Afr = (ushort_t*)d_ws;                         // 122880 B
  ushort_t* Bq  = (ushort_t*)((char*)d_ws + 131072);
  const size_t SB = (size_t)1152 * PLANE * 8 * 2;          // 42.5 MB per batch
  const bool both = (ws_size >= 131072 + 2 * SB);

  if (both) {
    bq_kernel<<<dim3(48, 16, 2), 256, 0, stream>>>(x, Bq, w, Afr);
    gemm_kernel<<<dim3(864, 1, 2), 128, 0, stream>>>(Bq, Afr, bias, out);
  } else {
    for (int b = 0; b < 2; ++b) {
      bq_kernel<<<dim3(48, 16, 1), 256, 0, stream>>>(x + (size_t)b * 32 * V3, Bq, w, Afr);
      gemm_kernel<<<dim3(864, 1, 1), 128, 0, stream>>>(Bq, Afr, bias,
                                                       out + (size_t)b * NO * V3);
    }
  }
}

// Round 7
// 150.325 us; speedup vs baseline: 1.0302x; 1.0302x over previous
//
#include <hip/hip_runtime.h>
#include <stdint.h>

#define V3 110592        // 48*48*48
#define PLANE 2304       // 48*48
#define NO 64

typedef unsigned short ushort_t;
typedef __attribute__((ext_vector_type(8))) short short8v;
typedef __attribute__((ext_vector_type(4))) float float4v;

__device__ __forceinline__ uint32_t f2bf1(float f) {
  uint32_t u = __float_as_uint(f);
  u += 0x7FFFu + ((u >> 16) & 1u);   // RNE
  return u >> 16;
}
__device__ __forceinline__ uint32_t pack2(float a, float b) {
  return f2bf1(a) | (f2bf1(b) << 16);
}

// prep folded into bq: blocks (x, y<5, z==0) cover idx = (y*48+x)*256+tid
// = exactly [0, 61440). Afr[g][m][8] bf16, kk = dzi*192 + i*6 + qi, g=kk/8.
__device__ __forceinline__ void prep_body(const float* __restrict__ w,
                                          ushort_t* __restrict__ Afr, int idx) {
  int r = idx & 7, m = (idx >> 3) & 63, g = idx >> 9;
  int kk = g * 8 + r;
  int dzi = kk / 192, k2 = kk % 192;
  int i = k2 / 6, qi = k2 % 6;
  const int Q[6] = {0, 1, 2, 4, 5, 8};
  const int pidx[13] = {0, 1, 2, 3, 4, 5, 6, 0, 7, 8, 0, 0, 9};  // r2 -> shell
  int dz = dzi - 2;
  int p = pidx[Q[qi] + dz * dz];
  Afr[idx] = (ushort_t)f2bf1(0.28209479177387814f * w[(m * 32 + i) * 10 + p]);
}

// ---------- pass 1: per-plane 2D class sums; NO LDS, NO barriers ----------
// R4 (verified): two-phase (all 40 loads first, then shfl/reduce/store) took
// bq to ~its memory floor (~16-18 us per batch). Kept as-is.
__global__ __launch_bounds__(256, 4) void bq_kernel(const float* __restrict__ x,
                                                    ushort_t* __restrict__ Bq,
                                                    const float* __restrict__ w,
                                                    ushort_t* __restrict__ Afr) {
  const int tid = threadIdx.x;
  if (blockIdx.z == 0 && blockIdx.y < 5)
    prep_body(w, Afr, (blockIdx.y * 48 + blockIdx.x) * 256 + tid);

  const int lane = tid & 63;
  const int strip = tid >> 6;                    // 0..3 within block
  const int d = blockIdx.x;                      // 0..47
  const int ig = blockIdx.y & 7;                 // 0..7 channel group
  const int half = blockIdx.y >> 3;              // 0..1 strip half
  const float* xb = x + (size_t)blockIdx.z * 32 * V3;
  ushort_t* Bqb = Bq + (size_t)blockIdx.z * ((size_t)1152 * PLANE * 8);

  const int h0 = (half * 4 + strip) * 6;         // 6-row strip base
  const int gw = lane - 2;
  const bool okw = (gw >= 0 && gw < 48);
  const int sl1 = lane > 0 ? lane - 1 : 0;
  const int sl2 = lane > 1 ? lane - 2 : 0;
  const int sr1 = lane < 63 ? lane + 1 : 63;
  const int sr2 = lane < 62 ? lane + 2 : 63;
  const bool okst = (lane >= 2 && lane <= 49);

  const float* px[4];
#pragma unroll
  for (int ii = 0; ii < 4; ++ii)
    px[ii] = xb + ((size_t)(ig * 4 + ii) * 48 + d) * PLANE + gw;

  // phase 1: all loads in flight (independent addresses, one vmcnt chain)
  float v[10][4];
#pragma unroll
  for (int r = 0; r < 10; ++r) {
    const int gh = h0 - 2 + r;
    const bool okv = okw && (gh >= 0) && (gh < 48);
#pragma unroll
    for (int ii = 0; ii < 4; ++ii)
      v[r][ii] = okv ? px[ii][gh * 48] : 0.f;
  }

  // phase 2: shfl class-sums with rolling windows; a0 terms read v[] directly
  float s1[4][5], s4[4][5];
#pragma unroll
  for (int r = 0; r < 10; ++r) {
    const int slot = r % 5;
#pragma unroll
    for (int ii = 0; ii < 4; ++ii) {
      float val = v[r][ii];
      float vl1 = __shfl(val, sl1);
      float vr1 = __shfl(val, sr1);
      float vl2 = __shfl(val, sl2);
      float vr2 = __shfl(val, sr2);
      s1[ii][slot] = vl1 + vr1;                  // dx^2 = 1
      s4[ii][slot] = vl2 + vr2;                  // dx^2 = 4
    }
    if (r >= 4) {
      const int j0 = (r - 4) % 5, j1 = (r - 3) % 5, j2 = (r - 2) % 5,
                j3 = (r - 1) % 5, j4 = r % 5;    // j = dy offset 0..4
      uint32_t dw[12];
#pragma unroll
      for (int ii = 0; ii < 4; ++ii) {
        float B0 = v[r - 2][ii];
        float B1 = s1[ii][j2] + v[r - 3][ii] + v[r - 1][ii];
        float B2 = s1[ii][j1] + s1[ii][j3];
        float B3 = s4[ii][j2] + v[r - 4][ii] + v[r][ii];
        float B4 = s4[ii][j1] + s4[ii][j3] + s1[ii][j0] + s1[ii][j4];
        float B5 = s4[ii][j0] + s4[ii][j4];
        dw[ii * 3 + 0] = pack2(B0, B1);
        dw[ii * 3 + 1] = pack2(B2, B3);
        dw[ii * 3 + 2] = pack2(B4, B5);
      }
      if (okst) {
        const int n = (h0 + r - 4) * 48 + gw;
        const size_t gb = (size_t)(d * 24 + ig * 3);
        uint4 c0 = {dw[0], dw[1], dw[2], dw[3]};
        uint4 c1 = {dw[4], dw[5], dw[6], dw[7]};
        uint4 c2 = {dw[8], dw[9], dw[10], dw[11]};
        *(uint4*)(Bqb + ((gb + 0) * PLANE + n) * 8) = c0;
        *(uint4*)(Bqb + ((gb + 1) * PLANE + n) * 8) = c1;
        *(uint4*)(Bqb + ((gb + 2) * PLANE + n) * 8) = c2;
      }
    }
  }
}

// ---------- pass 2: dz-reuse GEMM ----------
// R7 REWRITE. Old: each (d, ncols) block re-read 5 Bq planes from L2, 1 KB
// B-frag -> 4 MFMA; every prefetch scheme collapsed (R3-R6: VGPR 56-72) and
// MfmaUtil pinned at ~18%. New: block owns D=6 consecutive output planes
// (8 groups <-> 8 XCDs via b&7) x 64 cols. Per wave: acc[6][4] (96 VGPR);
// per ks-slice, A-frags for all 5 dz x 4 mt (80 VGPR, loop-INVARIANT over
// planes -> compiler hoists reliably, unlike pipelines). Each source plane's
// B-frag feeds up to 20 MFMA (5x more). B L2-volume drops 3x ((D+4)/D vs 5),
// load-issue per MFMA drops 5x; even fully-serialized B-load latency per ks
// (10 x ~250cy) < the ks's MFMA stream (120 MFMA ~ 2330 SIMD-cy) -> robust
// to load-sinking. Plane validity = wave-uniform branch; all acc/A indices
// compile-time (no scratch). out[d0+j] over planes p, dzi = p-(d0+j)+2 in
// [0,4], p clipped to [0,48) == reference's lo/hi clamp.
__global__ __launch_bounds__(256, 2) void gemm_kernel(const ushort_t* __restrict__ Bq,
                                                      const ushort_t* __restrict__ Afr,
                                                      const float* __restrict__ bias,
                                                      float* __restrict__ out) {
  const int tid = threadIdx.x;
  const int lane = tid & 63, wi = tid >> 6;      // 4 waves
  const int quad = lane >> 4, m15 = lane & 15;
  const int b = blockIdx.x;
  const int g = b & 7;                           // d-group == XCD
  const int s = b >> 3;                          // batch*36 + nbl
  const int batch = s / 36;
  const int nbl = s % 36;
  const int d0 = g * 6;
  const int n0 = nbl * 64 + wi * 16;
  const ushort_t* Bqb = Bq + (size_t)batch * ((size_t)1152 * PLANE * 8);
  float* outb = out + (size_t)batch * (size_t)NO * V3;

  float4v acc[6][4];                             // [j = d-d0][mt]
#pragma unroll
  for (int j = 0; j < 6; ++j)
#pragma unroll
    for (int mt = 0; mt < 4; ++mt) acc[j][mt] = (float4v){0.f, 0.f, 0.f, 0.f};

  short8v a[5][4];                               // [dzi][mt], per-ks resident

  for (int ks = 0; ks < 6; ++ks) {               // 32-k slice within a plane
    // A-frags: invariant over the plane sweep; same addrs for ALL waves ->
    // L1-hot. a[dzi][mt] covers kk = dzi*192 + ks*32 + quad*8 + (0..7).
#pragma unroll
    for (int dzi = 0; dzi < 5; ++dzi)
#pragma unroll
      for (int mt = 0; mt < 4; ++mt)
        a[dzi][mt] = *(const short8v*)(
            Afr + ((size_t)((dzi * 24 + ks * 4 + quad)) * 64 + mt * 16 + m15) * 8);

    // plane sweep: p = d0-2+pp; static j-window per pp: j in [pp-4, pp]
#pragma unroll
    for (int pp = 0; pp < 10; ++pp) {
      const int p = d0 - 2 + pp;
      if (p >= 0 && p < 48) {                    // wave-uniform
        short8v bf = *(const short8v*)(
            Bqb + ((size_t)(p * 24 + ks * 4 + quad) * PLANE + n0 + m15) * 8);
        const int jlo = (pp > 4) ? pp - 4 : 0;
        const int jhi = (pp < 5) ? pp : 5;
#pragma unroll
        for (int j = jlo; j <= jhi; ++j) {       // dzi = pp - j, compile-time
#pragma unroll
          for (int mt = 0; mt < 4; ++mt)
            acc[j][mt] = __builtin_amdgcn_mfma_f32_16x16x32_bf16(
                a[pp - j][mt], bf, acc[j][mt], 0, 0, 0);
        }
      }
    }
  }

  // C/D: col(n) = lane&15, row(m) = quad*4 + reg
#pragma unroll
  for (int j = 0; j < 6; ++j) {
    const int vb = (d0 + j) * PLANE + n0 + m15;
#pragma unroll
    for (int mt = 0; mt < 4; ++mt) {
#pragma unroll
      for (int r = 0; r < 4; ++r) {
        int m = mt * 16 + quad * 4 + r;
        outb[(size_t)m * V3 + vb] = acc[j][mt][r] + bias[m];
      }
    }
  }
}

extern "C" void kernel_launch(void* const* d_in, const int* in_sizes, int n_in,
                              void* d_out, int out_size, void* d_ws, size_t ws_size,
                              hipStream_t stream) {
  const float* x    = (const float*)d_in[0];   // [2,32,1,48,48,48]
  const float* w    = (const float*)d_in[1];   // [64,32,1,1,1,10]
  const float* bias = (const float*)d_in[2];   // [64]
  float* out = (float*)d_out;                  // [2,64,1,48,48,48]

  ushort_t* Afr = (ushort_t*)d_ws;                         // 122880 B
  ushort_t* Bq  = (ushort_t*)((char*)d_ws + 131072);
  const size_t SB = (size_t)1152 * PLANE * 8 * 2;          // 42.5 MB per batch
  const bool both = (ws_size >= 131072 + 2 * SB);

  if (both) {
    bq_kernel<<<dim3(48, 16, 2), 256, 0, stream>>>(x, Bq, w, Afr);
    gemm_kernel<<<dim3(576, 1, 1), 256, 0, stream>>>(Bq, Afr, bias, out);
  } else {
    for (int b = 0; b < 2; ++b) {
      bq_kernel<<<dim3(48, 16, 1), 256, 0, stream>>>(x + (size_t)b * 32 * V3, Bq, w, Afr);
      gemm_kernel<<<dim3(288, 1, 1), 256, 0, stream>>>(Bq, Afr, bias,
                                                       out + (size_t)b * NO * V3);
    }
  }
}